// Round 9
// baseline (340.345 us; speedup 1.0000x reference)
//
#include <hip/hip_runtime.h>
#include <hip/hip_bf16.h>

#define N_NODES 150000
#define CDIM 256
#define DIM 256
#define BM 32

typedef float f32x4 __attribute__((ext_vector_type(4)));
typedef short bf16x8 __attribute__((ext_vector_type(8)));
typedef unsigned short u16x4 __attribute__((ext_vector_type(4)));

// ws layout (bytes)
#define WS_CB 0          // bf16 B fragments: [32][256][8] ushort = 131072 B
#define WS_SC 131072     // sc[256] f32
#define WS_RC2 132096    // rc2[256] = 2/(1-sc) f32
#define WS_GACC 133120   // gacc[256] f32
#define WS_MSUM 134144   // masksum[1] f32

__device__ __forceinline__ unsigned short f2bf(float f) {
  unsigned u = __float_as_uint(f);
  u += 0x7FFFu + ((u >> 16) & 1u);   // round-to-nearest-even
  return (unsigned short)(u >> 16);
}

// blocks 0..255: centroid row b -> bf16 frag layout + sc[b] + rc2[b]
// blocks 256..319: grid-stride sum of mask -> msum
__global__ void cd_prep(const float* __restrict__ cw, const float* __restrict__ mask,
                        unsigned short* __restrict__ cb, float* __restrict__ sc,
                        float* __restrict__ rc2, float* __restrict__ msum) {
  int b = blockIdx.x;
  int t = threadIdx.x;
  int wave = t >> 6, lane = t & 63;
  __shared__ float red[4];
  if (b < CDIM) {
    float v = cw[b * DIM + t];
    cb[(size_t)(t >> 3) * (CDIM * 8) + b * 8 + (t & 7)] = f2bf(v);
    float ss = v * v;
    #pragma unroll
    for (int off = 32; off >= 1; off >>= 1) ss += __shfl_xor(ss, off);
    if (lane == 0) red[wave] = ss;
    __syncthreads();
    if (t == 0) {
      float s = red[0] + red[1] + red[2] + red[3];
      sc[b] = s;
      rc2[b] = 2.0f / (1.0f - s);
    }
  } else {
    int idx = (b - CDIM) * 256 + t;
    const int stride = 64 * 256;
    float s = 0.f;
    for (int i = idx; i < N_NODES; i += stride) s += mask[i];
    #pragma unroll
    for (int off = 32; off >= 1; off >>= 1) s += __shfl_xor(s, off);
    if (lane == 0) red[wave] = s;
    __syncthreads();
    if (t == 0) atomicAdd(msum, red[0] + red[1] + red[2] + red[3]);
  }
}

__global__ __launch_bounds__(256, 4)
void cd_main(const float* __restrict__ x, const float* __restrict__ mask,
             const unsigned short* __restrict__ cb, const float* __restrict__ sc,
             const float* __restrict__ rc2, float* __restrict__ gacc,
             float* __restrict__ out1) {
  // A-tile bf16 fragments [kfrag(32)][row(32)][8] = 16 KB. Both the u16x4
  // staging writes and the b128 frag reads hit the 32 banks at their
  // round-count floor (verified by hand: 4*row + 2*(sub&1) pattern covers
  // all banks exactly).
  __shared__ unsigned short ab[32 * BM * 8];
  __shared__ float sxl[BM];
  __shared__ float mskl[BM];

  const int t = threadIdx.x;
  const long m0 = (long)blockIdx.x * BM;

  // ---- stage x-tile -> LDS; exact f32 sx; mask -> LDS ----
  {
    const int row = t >> 3;          // 0..31
    const int sub = t & 7;
    const long grow = m0 + row;
    const bool ok = grow < N_NODES;
    const float* px = x + grow * DIM + sub * 4;
    f32x4 v[8];
    #pragma unroll
    for (int i = 0; i < 8; ++i)
      v[i] = ok ? *(const f32x4*)(px + i * 32) : f32x4{0.f, 0.f, 0.f, 0.f};
    float ss = 0.f;
    #pragma unroll
    for (int i = 0; i < 8; ++i) {
      ss = fmaf(v[i].x, v[i].x, ss); ss = fmaf(v[i].y, v[i].y, ss);
      ss = fmaf(v[i].z, v[i].z, ss); ss = fmaf(v[i].w, v[i].w, ss);
      u16x4 b;
      b[0] = f2bf(v[i].x); b[1] = f2bf(v[i].y);
      b[2] = f2bf(v[i].z); b[3] = f2bf(v[i].w);
      const int kf = (sub >> 1) + i * 4;     // (col/8), col = sub*4 + i*32
      *(u16x4*)(ab + ((size_t)kf * BM + row) * 8 + (sub & 1) * 4) = b;
    }
    ss += __shfl_xor(ss, 1);
    ss += __shfl_xor(ss, 2);
    ss += __shfl_xor(ss, 4);
    if (sub == 0) {
      sxl[row] = ss;
      mskl[row] = ok ? mask[grow] : 0.f;
    }
  }
  __syncthreads();

  // ---- MFMA: wave w owns 32 rows x 64 cols, software-pipelined B loads ----
  const int lane = t & 63;
  const int w = t >> 6;
  const int q = lane >> 4;
  const int ln = lane & 15;
  const int c0 = w * 64;

  bf16x8 bfc[4], bfn[4];
  #pragma unroll
  for (int nt = 0; nt < 4; ++nt)
    bfc[nt] = *(const bf16x8*)(cb + (size_t)q * (CDIM * 8) + (c0 + nt * 16 + ln) * 8);

  f32x4 acc[2][4] = {};
  #pragma unroll
  for (int kt = 0; kt < 8; ++kt) {
    if (kt < 7) {
      #pragma unroll
      for (int nt = 0; nt < 4; ++nt)
        bfn[nt] = *(const bf16x8*)(cb + (size_t)((kt + 1) * 4 + q) * (CDIM * 8) + (c0 + nt * 16 + ln) * 8);
    }
    bf16x8 af0 = *(const bf16x8*)(ab + ((size_t)(kt * 4 + q) * BM + ln) * 8);
    bf16x8 af1 = *(const bf16x8*)(ab + ((size_t)(kt * 4 + q) * BM + 16 + ln) * 8);
    #pragma unroll
    for (int nt = 0; nt < 4; ++nt)
      acc[0][nt] = __builtin_amdgcn_mfma_f32_16x16x32_bf16(af0, bfc[nt], acc[0][nt], 0, 0, 0);
    #pragma unroll
    for (int nt = 0; nt < 4; ++nt)
      acc[1][nt] = __builtin_amdgcn_mfma_f32_16x16x32_bf16(af1, bfc[nt], acc[1][nt], 0, 0, 0);
    if (kt < 7) {
      #pragma unroll
      for (int nt = 0; nt < 4; ++nt) bfc[nt] = bfn[nt];
    }
  }

  // ---- epilogue ----
  float scv[4], rc2v[4];
  #pragma unroll
  for (int nt = 0; nt < 4; ++nt) {
    scv[nt] = sc[c0 + nt * 16 + ln];
    rc2v[nt] = rc2[c0 + nt * 16 + ln];
  }

  float pc[4] = {0.f, 0.f, 0.f, 0.f};
  #pragma unroll
  for (int mt = 0; mt < 2; ++mt) {
    float sxe[4], rxi[4], mke[4];
    long rows[4];
    #pragma unroll
    for (int i = 0; i < 4; ++i) {
      const int rloc = mt * 16 + q * 4 + i;       // C/D: row = 4*(lane>>4)+reg
      sxe[i] = sxl[rloc];
      rows[i] = m0 + rloc;
      mke[i] = mskl[rloc] * 0.6931471805599453f;  // fold ln2 into mask
      rxi[i] = __builtin_amdgcn_rcpf(1.0f - sxe[i]);  // den >= 0.18, clamp never binds
    }
    #pragma unroll
    for (int nt = 0; nt < 4; ++nt) {
      const int col = c0 + nt * 16 + ln;          // C/D: col = lane&15
      #pragma unroll
      for (int i = 0; i < 4; ++i) {
        float xc = acc[mt][nt][i];
        float sq = fmaxf(fmaf(-2.0f, xc, sxe[i] + scv[nt]), 0.0f);
        float z = fmaf(sq * rxi[i], rc2v[nt], 1.0f);
        z = fmaxf(z, 1.0f + 1e-7f);
        float t2 = z + sqrtf(fmaf(z, z, -1.0f));
        float o = __log2f(t2) * mke[i];
        if (rows[i] < N_NODES) out1[rows[i] * CDIM + col] = o;
        pc[nt] += o;
      }
    }
  }

  #pragma unroll
  for (int nt = 0; nt < 4; ++nt) {
    float s = pc[nt];
    s += __shfl_xor(s, 16);
    s += __shfl_xor(s, 32);
    if (lane < 16) atomicAdd(gacc + c0 + nt * 16 + ln, s);
  }
}

__global__ void cd_final(const float* __restrict__ gacc, const float* __restrict__ msum,
                         float* __restrict__ out0) {
  int t = threadIdx.x;
  out0[t] = gacc[t] / msum[0];
}

extern "C" void kernel_launch(void* const* d_in, const int* in_sizes, int n_in,
                              void* d_out, int out_size, void* d_ws, size_t ws_size,
                              hipStream_t stream) {
  const float* x    = (const float*)d_in[0];   // [150000,256]
  const float* mask = (const float*)d_in[1];   // [150000,1]
  const float* cw   = (const float*)d_in[2];   // [256,256]
  float* out = (float*)d_out;                  // [256] ++ [150000*256]
  char* ws = (char*)d_ws;
  unsigned short* cb = (unsigned short*)(ws + WS_CB);
  float* sc   = (float*)(ws + WS_SC);
  float* rc2  = (float*)(ws + WS_RC2);
  float* gacc = (float*)(ws + WS_GACC);
  float* msum = (float*)(ws + WS_MSUM);

  hipMemsetAsync(ws + WS_GACC, 0, 256 * 4 + 4, stream);
  cd_prep<<<320, 256, 0, stream>>>(cw, mask, cb, sc, rc2, msum);
  const int nblocks = (N_NODES + BM - 1) / BM;   // 4688
  cd_main<<<nblocks, 256, 0, stream>>>(x, mask, cb, sc, rc2, gacc, out + 256);
  cd_final<<<1, 256, 0, stream>>>(gacc, msum, out);
}